// Round 19
// baseline (62.542 us; speedup 1.0000x reference)
//
#include <hip/hip_runtime.h>

#ifndef FLT_MAX
#define FLT_MAX 3.402823466e+38f
#endif

typedef _Float16 h2 __attribute__((ext_vector_type(2)));

__device__ __forceinline__ float sel3(int i, float a, float b, float c) {
    return i == 0 ? a : (i == 1 ? b : c);
}
__device__ __forceinline__ float sel4(int i, float a, float b, float c, float d) {
    return i == 0 ? a : (i == 1 ? b : (i == 2 ? c : d));
}

// numpy-order exact d2: ((dx*dx + dy*dy) + dz*dz), RNE, NO fma — bit-identical
// to the reference's evaluation order.
__device__ __forceinline__ float d2np(float ax, float ay, float az,
                                      float bx, float by, float bz) {
    const float dx = __fsub_rn(ax, bx);
    const float dy = __fsub_rn(ay, by);
    const float dz = __fsub_rn(az, bz);
    return __fadd_rn(__fadd_rn(__fmul_rn(dx, dx), __fmul_rn(dy, dy)),
                     __fmul_rn(dz, dz));
}

// Pack 2 f32 -> f16x2 in ONE instruction (v_cvt_pkrtz_f16_f32, RTZ; input
// negation folds into the op's source modifier).
__device__ __forceinline__ h2 pkrtz(float a, float b) {
    return __builtin_bit_cast(h2, __builtin_amdgcn_cvt_pkrtz(a, b));
}
__device__ __forceinline__ h2 bch2(unsigned u) { return __builtin_bit_cast(h2, u); }
__device__ __forceinline__ unsigned bcu(h2 v) { return __builtin_bit_cast(unsigned, v); }

// FOUR edges per wave (16-lane group n owns edge n); lane 16n+t owns rows
// 4t..4t+3 and cols 4t..4t+3 (R9 structure, validated). Phase 1: f16 packed
// approximate scan in NATIVE h2 arithmetic (compiler emits v_pk_*_f16 and is
// free to interleave the 16 independent accumulator chains — R18's asm blocks
// serialized and halved VALUBusy). Phase 2: conservative window (rigorous f16
// RTZ error bound, ~1.75x margin, x2 in T) -> candidate rows re-scanned
// EXACTLY in f32 numpy op order, rows ascending, first-col ballots -> exact
// numpy first-flattened-index argmin semantics regardless of filter noise.
__global__ __launch_bounds__(256, 4) void clustgeo_f16h2(
    const float* __restrict__ data,
    const int*   __restrict__ clusts,
    const int*   __restrict__ eidx,
    float*       __restrict__ out,
    int E)
{
    const int wave = threadIdx.x >> 6;
    const int lane = threadIdx.x & 63;
    const int t    = lane & 15;
    const int gsh  = lane & 48;
    const int e    = blockIdx.x * 16 + wave * 4 + (lane >> 4);
    const int ec   = e < E ? e : (E - 1);

    __shared__ __align__(16) unsigned sx[4][4][112];   // 3 planes x 32 dwords + pad

    const int ca = eidx[ec];
    const int cb = eidx[E + ec];
    const int4 P1 = *reinterpret_cast<const int4*>(clusts + ca * 64 + 4 * t);
    const int4 P2 = *reinterpret_cast<const int4*>(clusts + cb * 64 + 4 * t);
    const float4 q10 = *reinterpret_cast<const float4*>(data + (size_t)P1.x * 4);
    const float4 q11 = *reinterpret_cast<const float4*>(data + (size_t)P1.y * 4);
    const float4 q12 = *reinterpret_cast<const float4*>(data + (size_t)P1.z * 4);
    const float4 q13 = *reinterpret_cast<const float4*>(data + (size_t)P1.w * 4);
    const float4 q20 = *reinterpret_cast<const float4*>(data + (size_t)P2.x * 4);
    const float4 q21 = *reinterpret_cast<const float4*>(data + (size_t)P2.y * 4);
    const float4 q22 = *reinterpret_cast<const float4*>(data + (size_t)P2.z * 4);
    const float4 q23 = *reinterpret_cast<const float4*>(data + (size_t)P2.w * 4);
    const float r0x=q10.y, r0y=q10.z, r0z=q10.w;
    const float r1x=q11.y, r1y=q11.z, r1z=q11.w;
    const float r2x=q12.y, r2y=q12.z, r2z=q12.w;
    const float r3x=q13.y, r3y=q13.z, r3z=q13.w;
    const float c0x=q20.y, c0y=q20.z, c0z=q20.w;
    const float c1x=q21.y, c1y=q21.z, c1z=q21.w;
    const float c2x=q22.y, c2y=q22.z, c2z=q22.w;
    const float c3x=q23.y, c3y=q23.z, c3z=q23.w;

    // Stage NEGATED f16 cols: plane p at dword p*32; colpair (4t,4t+1) at 2t.
    unsigned* slice = &sx[wave][lane >> 4][0];
    slice[2*t]      = bcu(pkrtz(-c0x, -c1x));  slice[2*t + 1]      = bcu(pkrtz(-c2x, -c3x));
    slice[32 + 2*t] = bcu(pkrtz(-c0y, -c1y));  slice[32 + 2*t + 1] = bcu(pkrtz(-c2y, -c3y));
    slice[64 + 2*t] = bcu(pkrtz(-c0z, -c1z));  slice[64 + 2*t + 1] = bcu(pkrtz(-c2z, -c3z));
    // No barrier: each group reads only its own slice; same-wave LDS RAW is
    // ordered by compiler-inserted lgkmcnt waits (validated R3-R18).

    // Row broadcasts {r,r} in h2.
    const h2 rrx[4] = {pkrtz(r0x, r0x), pkrtz(r1x, r1x), pkrtz(r2x, r2x), pkrtz(r3x, r3x)};
    const h2 rry[4] = {pkrtz(r0y, r0y), pkrtz(r1y, r1y), pkrtz(r2y, r2y), pkrtz(r3y, r3y)};
    const h2 rrz[4] = {pkrtz(r0z, r0z), pkrtz(r1z, r1z), pkrtz(r2z, r2z), pkrtz(r3z, r3z)};

    const uint4* SU = reinterpret_cast<const uint4*>(slice);   // plane p: [p*8+g]

    h2 acc[4][4];   // [row][colpair] — 16 independent chains (constant-indexed)
    #pragma unroll
    for (int r = 0; r < 4; ++r)
        #pragma unroll
        for (int c = 0; c < 4; ++c) acc[r][c] = bch2(0x7C007C00u);  // {+inf,+inf}

    #pragma unroll 2
    for (int g = 0; g < 8; ++g) {       // 8 cols (4 colpairs) per iteration
        const uint4 X = SU[g];
        const uint4 Y = SU[8 + g];
        const uint4 Z = SU[16 + g];
        const h2 ncx[4] = {bch2(X.x), bch2(X.y), bch2(X.z), bch2(X.w)};
        const h2 ncy[4] = {bch2(Y.x), bch2(Y.y), bch2(Y.z), bch2(Y.w)};
        const h2 ncz[4] = {bch2(Z.x), bch2(Z.y), bch2(Z.z), bch2(Z.w)};
        #pragma unroll
        for (int r = 0; r < 4; ++r) {
            #pragma unroll
            for (int c = 0; c < 4; ++c) {
                const h2 dx = rrx[r] + ncx[c];
                const h2 dy = rry[r] + ncy[c];
                const h2 dz = rrz[r] + ncz[c];
                const h2 d2 = __builtin_elementwise_fma(dx, dx,
                              __builtin_elementwise_fma(dy, dy, dz * dz));
                acc[r][c] = __builtin_elementwise_min(acc[r][c], d2);
            }
        }
    }

    // Per-row approx mins (f32).
    float rm[4];
    #pragma unroll
    for (int r = 0; r < 4; ++r) {
        const h2 m = __builtin_elementwise_min(
            __builtin_elementwise_min(acc[r][0], acc[r][1]),
            __builtin_elementwise_min(acc[r][2], acc[r][3]));
        rm[r] = fminf((float)m.x, (float)m.y);
    }
    const float rm0 = rm[0], rm1 = rm[1], rm2 = rm[2], rm3 = rm[3];

    float bm = fminf(fminf(rm0, rm1), fminf(rm2, rm3));
    #pragma unroll
    for (int off = 8; off; off >>= 1) bm = fminf(bm, __shfl_xor(bm, off, 64));

    // Max |coord| over both clusters (group reduce) for the error bound.
    float Ml = fmaxf(fmaxf(fmaxf(fabsf(r0x), fabsf(r0y)), fmaxf(fabsf(r0z), fabsf(r1x))),
               fmaxf(fmaxf(fabsf(r1y), fabsf(r1z)), fmaxf(fabsf(r2x), fabsf(r2y))));
    Ml = fmaxf(Ml, fmaxf(fmaxf(fabsf(r2z), fabsf(r3x)), fmaxf(fabsf(r3y), fabsf(r3z))));
    Ml = fmaxf(Ml, fmaxf(fmaxf(fabsf(c0x), fabsf(c0y)), fmaxf(fabsf(c0z), fabsf(c1x))));
    Ml = fmaxf(Ml, fmaxf(fmaxf(fabsf(c1y), fabsf(c1z)), fmaxf(fabsf(c2x), fabsf(c2y))));
    Ml = fmaxf(Ml, fmaxf(fmaxf(fabsf(c2z), fabsf(c3x)), fmaxf(fabsf(c3y), fabsf(c3z))));
    #pragma unroll
    for (int off = 8; off; off >>= 1) Ml = fmaxf(Ml, __shfl_xor(Ml, off, 64));

    // RTZ-input bound: |d2_h-d2| <~ 4*sqrt(3)*2^-10*M*sqrt(d2) + 3*2^-10*d2
    // + slack  => dominant 0.0068*M*sqrt(d2). Coefficient 0.012 = ~1.75x
    // margin; window doubles it again.
    const float eps = 0.012f * (Ml * sqrtf(bm) + bm) + 1e-3f;
    const float T = bm + 2.0f * eps;

    // Candidate rows (row = 4t + s; ascending = (t,s) lex).
    int fb = (rm0 <= T ? 1 : 0) | (rm1 <= T ? 2 : 0) |
             (rm2 <= T ? 4 : 0) | (rm3 <= T ? 8 : 0);

    float bestVal = FLT_MAX;
    int bestRow = 0, bestCol = 0;
    while (true) {
        int rl = fb ? (4 * t + __builtin_ctz((unsigned)fb)) : 999;
        int rstar = rl;
        #pragma unroll
        for (int off = 8; off; off >>= 1) {
            const int o = __shfl_xor(rstar, off, 64);
            rstar = o < rstar ? o : rstar;
        }
        if (!__ballot(rstar != 999)) break;   // all groups done
        if (rstar != 999) {
            if (rl == rstar) fb &= fb - 1;    // unique owner clears its bit
            const int ss = rstar & 3, tt = rstar >> 2;
            const float vx = __shfl(sel4(ss, r0x, r1x, r2x, r3x), gsh + tt, 64);
            const float vy = __shfl(sel4(ss, r0y, r1y, r2y, r3y), gsh + tt, 64);
            const float vz = __shfl(sel4(ss, r0z, r1z, r2z, r3z), gsh + tt, 64);
            const float e0 = d2np(vx, vy, vz, c0x, c0y, c0z);
            const float e1 = d2np(vx, vy, vz, c1x, c1y, c1z);
            const float e2 = d2np(vx, vy, vz, c2x, c2y, c2z);
            const float e3 = d2np(vx, vy, vz, c3x, c3y, c3z);
            float rmn = fminf(fminf(e0, e1), fminf(e2, e3));
            #pragma unroll
            for (int off = 8; off; off >>= 1) rmn = fminf(rmn, __shfl_xor(rmn, off, 64));
            if (rmn < bestVal) {   // strict <: earlier (ascending) row wins ties
                bestVal = rmn;
                bestRow = rstar;
                const unsigned h0 = (unsigned)(__ballot(e0 == rmn) >> gsh) & 0xFFFFu;
                const unsigned h1 = (unsigned)(__ballot(e1 == rmn) >> gsh) & 0xFFFFu;
                const unsigned h2m = (unsigned)(__ballot(e2 == rmn) >> gsh) & 0xFFFFu;
                const unsigned h3 = (unsigned)(__ballot(e3 == rmn) >> gsh) & 0xFFFFu;
                const int t2i = __builtin_ctz(h0 | h1 | h2m | h3);
                const int s2 = (h0 >> t2i) & 1 ? 0 : (h1 >> t2i) & 1 ? 1
                             : (h2m >> t2i) & 1 ? 2 : 3;
                bestCol = 4 * t2i + s2;       // first col attaining the row min
            }
        }
    }

    const int s1 = bestRow & 3, t1 = bestRow >> 2;
    const float v1x = __shfl(sel4(s1, r0x, r1x, r2x, r3x), gsh + t1, 64);
    const float v1y = __shfl(sel4(s1, r0y, r1y, r2y, r3y), gsh + t1, 64);
    const float v1z = __shfl(sel4(s1, r0z, r1z, r2z, r3z), gsh + t1, 64);
    const int s2c = bestCol & 3, t2c = bestCol >> 2;
    const float v2x = __shfl(sel4(s2c, c0x, c1x, c2x, c3x), gsh + t2c, 64);
    const float v2y = __shfl(sel4(s2c, c0y, c1y, c2y, c3y), gsh + t2c, 64);
    const float v2z = __shfl(sel4(s2c, c0z, c1z, c2z, c3z), gsh + t2c, 64);

    float dx = v1x - v2x, dy = v1y - v2y, dz = v1z - v2z;
    const float lend = sqrtf(dx * dx + dy * dy + dz * dz);
    if (lend > 0.f) {
        const float inv = 1.0f / lend;
        dx *= inv; dy *= inv; dz *= inv;
    }

    if (e < E) {
        float* orow = out + (size_t)e * 19;
        float o;
        if (t < 3)       o = sel3(t,     v1x, v1y, v1z);
        else if (t < 6)  o = sel3(t - 3, v2x, v2y, v2z);
        else if (t < 9)  o = sel3(t - 6, dx, dy, dz);
        else if (t == 9) o = lend;
        else {
            const int k = t - 10;
            o = sel3(k / 3, dx, dy, dz) * sel3(k % 3, dx, dy, dz);
        }
        orow[t] = o;
        if (t < 3) {
            const int k = t + 6;   // elements 16,17,18 = B[6..8]
            orow[16 + t] = sel3(k / 3, dx, dy, dz) * sel3(k % 3, dx, dy, dz);
        }
    }
}

extern "C" void kernel_launch(void* const* d_in, const int* in_sizes, int n_in,
                              void* d_out, int out_size, void* d_ws, size_t ws_size,
                              hipStream_t stream) {
    const float* data   = (const float*)d_in[0];
    const int*   clusts = (const int*)d_in[1];
    const int*   eidx   = (const int*)d_in[2];
    float*       out    = (float*)d_out;
    const int E = in_sizes[2] / 2;            // edge_index is (2, E)
    const int blocks = (E + 15) / 16;         // 16 edges per block (4 waves x 4)
    clustgeo_f16h2<<<blocks, 256, 0, stream>>>(data, clusts, eidx, out, E);
}

// Round 20
// 53.854 us; speedup vs baseline: 1.1613x; 1.1613x over previous
//
#include <hip/hip_runtime.h>

#ifndef FLT_MAX
#define FLT_MAX 3.402823466e+38f
#endif

typedef _Float16 h2 __attribute__((ext_vector_type(2)));

__device__ __forceinline__ float sel3(int i, float a, float b, float c) {
    return i == 0 ? a : (i == 1 ? b : c);
}
__device__ __forceinline__ float sel4(int i, float a, float b, float c, float d) {
    return i == 0 ? a : (i == 1 ? b : (i == 2 ? c : d));
}

// numpy-order exact d2: ((dx*dx + dy*dy) + dz*dz), RNE, NO fma — bit-identical
// to the reference's evaluation order.
__device__ __forceinline__ float d2np(float ax, float ay, float az,
                                      float bx, float by, float bz) {
    const float dx = __fsub_rn(ax, bx);
    const float dy = __fsub_rn(ay, by);
    const float dz = __fsub_rn(az, bz);
    return __fadd_rn(__fadd_rn(__fmul_rn(dx, dx), __fmul_rn(dy, dy)),
                     __fmul_rn(dz, dz));
}

__device__ __forceinline__ h2 pkrtz(float a, float b) {
    return __builtin_bit_cast(h2, __builtin_amdgcn_cvt_pkrtz(a, b));
}
__device__ __forceinline__ h2 bch2(unsigned u) { return __builtin_bit_cast(h2, u); }
__device__ __forceinline__ unsigned bcu(h2 v) { return __builtin_bit_cast(unsigned, v); }

// FOUR edges per wave (16-lane group n owns edge n); lane 16n+t owns rows
// 4t..4t+3 and cols 4t..4t+3. Phase 1: f16 packed approx scan (native h2).
// Phase 2: conservative window -> candidate rows; 4-SLOT PARALLEL refine
// (R19's serial per-row loop was ~600cyc latency x several iterations —
// this processes 4 candidate rows per iteration, 1 iteration typical).
// Exact f32 numpy-op-order recompute, rows ascending, first-col ballots ->
// exact numpy first-flattened-index argmin regardless of filter noise.
__global__ __launch_bounds__(256, 4) void clustgeo_f16p4(
    const float* __restrict__ data,
    const int*   __restrict__ clusts,
    const int*   __restrict__ eidx,
    float*       __restrict__ out,
    int E)
{
    const int wave = threadIdx.x >> 6;
    const int lane = threadIdx.x & 63;
    const int t    = lane & 15;
    const int gsh  = lane & 48;
    const int e    = blockIdx.x * 16 + wave * 4 + (lane >> 4);
    const int ec   = e < E ? e : (E - 1);

    __shared__ __align__(16) unsigned sx[4][4][112];   // 3 planes x 32 dwords + pad

    const int ca = eidx[ec];
    const int cb = eidx[E + ec];
    const int4 P1 = *reinterpret_cast<const int4*>(clusts + ca * 64 + 4 * t);
    const int4 P2 = *reinterpret_cast<const int4*>(clusts + cb * 64 + 4 * t);
    const float4 q10 = *reinterpret_cast<const float4*>(data + (size_t)P1.x * 4);
    const float4 q11 = *reinterpret_cast<const float4*>(data + (size_t)P1.y * 4);
    const float4 q12 = *reinterpret_cast<const float4*>(data + (size_t)P1.z * 4);
    const float4 q13 = *reinterpret_cast<const float4*>(data + (size_t)P1.w * 4);
    const float4 q20 = *reinterpret_cast<const float4*>(data + (size_t)P2.x * 4);
    const float4 q21 = *reinterpret_cast<const float4*>(data + (size_t)P2.y * 4);
    const float4 q22 = *reinterpret_cast<const float4*>(data + (size_t)P2.z * 4);
    const float4 q23 = *reinterpret_cast<const float4*>(data + (size_t)P2.w * 4);
    const float r0x=q10.y, r0y=q10.z, r0z=q10.w;
    const float r1x=q11.y, r1y=q11.z, r1z=q11.w;
    const float r2x=q12.y, r2y=q12.z, r2z=q12.w;
    const float r3x=q13.y, r3y=q13.z, r3z=q13.w;
    const float c0x=q20.y, c0y=q20.z, c0z=q20.w;
    const float c1x=q21.y, c1y=q21.z, c1z=q21.w;
    const float c2x=q22.y, c2y=q22.z, c2z=q22.w;
    const float c3x=q23.y, c3y=q23.z, c3z=q23.w;

    // Stage NEGATED f16 cols: plane p at dword p*32; colpair (4t,4t+1) at 2t.
    unsigned* slice = &sx[wave][lane >> 4][0];
    slice[2*t]      = bcu(pkrtz(-c0x, -c1x));  slice[2*t + 1]      = bcu(pkrtz(-c2x, -c3x));
    slice[32 + 2*t] = bcu(pkrtz(-c0y, -c1y));  slice[32 + 2*t + 1] = bcu(pkrtz(-c2y, -c3y));
    slice[64 + 2*t] = bcu(pkrtz(-c0z, -c1z));  slice[64 + 2*t + 1] = bcu(pkrtz(-c2z, -c3z));
    // No barrier: each group reads only its own slice; same-wave LDS RAW is
    // ordered by compiler-inserted lgkmcnt waits (validated R3-R19).

    const h2 rrx[4] = {pkrtz(r0x, r0x), pkrtz(r1x, r1x), pkrtz(r2x, r2x), pkrtz(r3x, r3x)};
    const h2 rry[4] = {pkrtz(r0y, r0y), pkrtz(r1y, r1y), pkrtz(r2y, r2y), pkrtz(r3y, r3y)};
    const h2 rrz[4] = {pkrtz(r0z, r0z), pkrtz(r1z, r1z), pkrtz(r2z, r2z), pkrtz(r3z, r3z)};

    const uint4* SU = reinterpret_cast<const uint4*>(slice);   // plane p: [p*8+g]

    h2 acc[4][4];
    #pragma unroll
    for (int r = 0; r < 4; ++r)
        #pragma unroll
        for (int c = 0; c < 4; ++c) acc[r][c] = bch2(0x7C007C00u);  // {+inf,+inf}

    #pragma unroll 2
    for (int g = 0; g < 8; ++g) {
        const uint4 X = SU[g];
        const uint4 Y = SU[8 + g];
        const uint4 Z = SU[16 + g];
        const h2 ncx[4] = {bch2(X.x), bch2(X.y), bch2(X.z), bch2(X.w)};
        const h2 ncy[4] = {bch2(Y.x), bch2(Y.y), bch2(Y.z), bch2(Y.w)};
        const h2 ncz[4] = {bch2(Z.x), bch2(Z.y), bch2(Z.z), bch2(Z.w)};
        #pragma unroll
        for (int r = 0; r < 4; ++r) {
            #pragma unroll
            for (int c = 0; c < 4; ++c) {
                const h2 dx = rrx[r] + ncx[c];
                const h2 dy = rry[r] + ncy[c];
                const h2 dz = rrz[r] + ncz[c];
                const h2 d2 = __builtin_elementwise_fma(dx, dx,
                              __builtin_elementwise_fma(dy, dy, dz * dz));
                acc[r][c] = __builtin_elementwise_min(acc[r][c], d2);
            }
        }
    }

    float rm[4];
    #pragma unroll
    for (int r = 0; r < 4; ++r) {
        const h2 m = __builtin_elementwise_min(
            __builtin_elementwise_min(acc[r][0], acc[r][1]),
            __builtin_elementwise_min(acc[r][2], acc[r][3]));
        rm[r] = fminf((float)m.x, (float)m.y);
    }

    float bm = fminf(fminf(rm[0], rm[1]), fminf(rm[2], rm[3]));
    #pragma unroll
    for (int off = 8; off; off >>= 1) bm = fminf(bm, __shfl_xor(bm, off, 64));

    // Max |coord| over both clusters for the f16 RTZ error bound.
    float Ml = fmaxf(fmaxf(fmaxf(fabsf(r0x), fabsf(r0y)), fmaxf(fabsf(r0z), fabsf(r1x))),
               fmaxf(fmaxf(fabsf(r1y), fabsf(r1z)), fmaxf(fabsf(r2x), fabsf(r2y))));
    Ml = fmaxf(Ml, fmaxf(fmaxf(fabsf(r2z), fabsf(r3x)), fmaxf(fabsf(r3y), fabsf(r3z))));
    Ml = fmaxf(Ml, fmaxf(fmaxf(fabsf(c0x), fabsf(c0y)), fmaxf(fabsf(c0z), fabsf(c1x))));
    Ml = fmaxf(Ml, fmaxf(fmaxf(fabsf(c1y), fabsf(c1z)), fmaxf(fabsf(c2x), fabsf(c2y))));
    Ml = fmaxf(Ml, fmaxf(fmaxf(fabsf(c2z), fabsf(c3x)), fmaxf(fabsf(c3y), fabsf(c3z))));
    #pragma unroll
    for (int off = 8; off; off >>= 1) Ml = fmaxf(Ml, __shfl_xor(Ml, off, 64));

    // RTZ bound: |d2_h-d2| <~ 4*sqrt(3)*2^-10*M*sqrt(d2) + 3*2^-11*d2 + slack
    // (dominant 0.0068*M*sqrt(d2)); 0.012 coefficient = ~1.75x margin, x2 in T.
    const float eps = 0.012f * (Ml * sqrtf(bm) + bm) + 1e-3f;
    const float T = bm + 2.0f * eps;

    // Candidate masks per row-slot (bit t of Ms => row 4t+s is a candidate).
    unsigned M0 = (unsigned)(__ballot(rm[0] <= T) >> gsh) & 0xFFFFu;
    unsigned M1 = (unsigned)(__ballot(rm[1] <= T) >> gsh) & 0xFFFFu;
    unsigned M2 = (unsigned)(__ballot(rm[2] <= T) >> gsh) & 0xFFFFu;
    unsigned M3 = (unsigned)(__ballot(rm[3] <= T) >> gsh) & 0xFFFFu;

    float bestVal = FLT_MAX;
    int bestRow = 0, bestCol = 0;
    while (true) {
        const unsigned anyg = M0 | M1 | M2 | M3;
        if (!__ballot(anyg != 0)) break;           // all groups exhausted

        // Extract up to 4 lowest candidate rows (scalar ops, no shfl).
        int rws[4], tts[4], sss[4];
        #pragma unroll
        for (int k = 0; k < 4; ++k) {
            const unsigned a = M0 | M1 | M2 | M3;
            if (a) {
                const int tt = __builtin_ctz(a);
                const int ss = (M0 >> tt) & 1 ? 0 : (M1 >> tt) & 1 ? 1
                             : (M2 >> tt) & 1 ? 2 : 3;
                rws[k] = 4 * tt + ss; tts[k] = tt; sss[k] = ss;
                const unsigned bit = 1u << tt;
                M0 = (ss == 0) ? (M0 & ~bit) : M0;
                M1 = (ss == 1) ? (M1 & ~bit) : M1;
                M2 = (ss == 2) ? (M2 & ~bit) : M2;
                M3 = (ss == 3) ? (M3 & ~bit) : M3;
            } else { rws[k] = -1; tts[k] = 0; sss[k] = 0; }
        }

        // Parallel refine of the 4 slots (independent chains, one reduce wave).
        float ev[4][4], rmn[4];
        #pragma unroll
        for (int k = 0; k < 4; ++k) {
            const float vx = __shfl(sel4(sss[k], r0x, r1x, r2x, r3x), gsh + tts[k], 64);
            const float vy = __shfl(sel4(sss[k], r0y, r1y, r2y, r3y), gsh + tts[k], 64);
            const float vz = __shfl(sel4(sss[k], r0z, r1z, r2z, r3z), gsh + tts[k], 64);
            ev[k][0] = d2np(vx, vy, vz, c0x, c0y, c0z);
            ev[k][1] = d2np(vx, vy, vz, c1x, c1y, c1z);
            ev[k][2] = d2np(vx, vy, vz, c2x, c2y, c2z);
            ev[k][3] = d2np(vx, vy, vz, c3x, c3y, c3z);
            rmn[k] = fminf(fminf(ev[k][0], ev[k][1]), fminf(ev[k][2], ev[k][3]));
        }
        #pragma unroll
        for (int off = 8; off; off >>= 1) {
            #pragma unroll
            for (int k = 0; k < 4; ++k)
                rmn[k] = fminf(rmn[k], __shfl_xor(rmn[k], off, 64));
        }
        // Winner among valid slots, ascending (strict < keeps earliest row).
        #pragma unroll
        for (int k = 0; k < 4; ++k) {
            if (rws[k] >= 0 && rmn[k] < bestVal) {
                bestVal = rmn[k];
                bestRow = rws[k];
                const unsigned h0 = (unsigned)(__ballot(ev[k][0] == rmn[k]) >> gsh) & 0xFFFFu;
                const unsigned h1 = (unsigned)(__ballot(ev[k][1] == rmn[k]) >> gsh) & 0xFFFFu;
                const unsigned h2m = (unsigned)(__ballot(ev[k][2] == rmn[k]) >> gsh) & 0xFFFFu;
                const unsigned h3 = (unsigned)(__ballot(ev[k][3] == rmn[k]) >> gsh) & 0xFFFFu;
                const int t2i = __builtin_ctz(h0 | h1 | h2m | h3);
                const int s2 = (h0 >> t2i) & 1 ? 0 : (h1 >> t2i) & 1 ? 1
                             : (h2m >> t2i) & 1 ? 2 : 3;
                bestCol = 4 * t2i + s2;
            }
        }
    }

    const int s1 = bestRow & 3, t1 = bestRow >> 2;
    const float v1x = __shfl(sel4(s1, r0x, r1x, r2x, r3x), gsh + t1, 64);
    const float v1y = __shfl(sel4(s1, r0y, r1y, r2y, r3y), gsh + t1, 64);
    const float v1z = __shfl(sel4(s1, r0z, r1z, r2z, r3z), gsh + t1, 64);
    const int s2c = bestCol & 3, t2c = bestCol >> 2;
    const float v2x = __shfl(sel4(s2c, c0x, c1x, c2x, c3x), gsh + t2c, 64);
    const float v2y = __shfl(sel4(s2c, c0y, c1y, c2y, c3y), gsh + t2c, 64);
    const float v2z = __shfl(sel4(s2c, c0z, c1z, c2z, c3z), gsh + t2c, 64);

    float dx = v1x - v2x, dy = v1y - v2y, dz = v1z - v2z;
    const float lend = sqrtf(dx * dx + dy * dy + dz * dz);
    if (lend > 0.f) {
        const float inv = 1.0f / lend;
        dx *= inv; dy *= inv; dz *= inv;
    }

    if (e < E) {
        float* orow = out + (size_t)e * 19;
        float o;
        if (t < 3)       o = sel3(t,     v1x, v1y, v1z);
        else if (t < 6)  o = sel3(t - 3, v2x, v2y, v2z);
        else if (t < 9)  o = sel3(t - 6, dx, dy, dz);
        else if (t == 9) o = lend;
        else {
            const int k = t - 10;
            o = sel3(k / 3, dx, dy, dz) * sel3(k % 3, dx, dy, dz);
        }
        orow[t] = o;
        if (t < 3) {
            const int k = t + 6;   // elements 16,17,18 = B[6..8]
            orow[16 + t] = sel3(k / 3, dx, dy, dz) * sel3(k % 3, dx, dy, dz);
        }
    }
}

extern "C" void kernel_launch(void* const* d_in, const int* in_sizes, int n_in,
                              void* d_out, int out_size, void* d_ws, size_t ws_size,
                              hipStream_t stream) {
    const float* data   = (const float*)d_in[0];
    const int*   clusts = (const int*)d_in[1];
    const int*   eidx   = (const int*)d_in[2];
    float*       out    = (float*)d_out;
    const int E = in_sizes[2] / 2;            // edge_index is (2, E)
    const int blocks = (E + 15) / 16;         // 16 edges per block (4 waves x 4)
    clustgeo_f16p4<<<blocks, 256, 0, stream>>>(data, clusts, eidx, out, E);
}

// Round 21
// 32.351 us; speedup vs baseline: 1.9332x; 1.6647x over previous
//
#include <hip/hip_runtime.h>

#ifndef FLT_MAX
#define FLT_MAX 3.402823466e+38f
#endif

typedef float v4f __attribute__((ext_vector_type(4)));

__device__ __forceinline__ float sel3(int i, float a, float b, float c) {
    return i == 0 ? a : (i == 1 ? b : c);
}
__device__ __forceinline__ float sel4(int i, float a, float b, float c, float d) {
    return i == 0 ? a : (i == 1 ? b : (i == 2 ? c : d));
}

// Deterministic d2 (sub,sub,sub, mul, fma, fma) — used identically in the
// scan and the phase-2 recompute, so values are bit-identical (ties exact).
__device__ __forceinline__ float d2f(float ax, float ay, float az,
                                     float bx, float by, float bz) {
    const float dx = __fsub_rn(ax, bx);
    const float dy = __fsub_rn(ay, by);
    const float dz = __fsub_rn(az, bz);
    return __builtin_fmaf(dx, dx, __builtin_fmaf(dy, dy, __fmul_rn(dz, dz)));
}

// FOUR edges per 64-lane wave; 16-lane group n owns edge n; lane 16n+t owns
// rows 4t..4t+3 of x1 and cols 4t..4t+3 of x2 (R9 structure, validated).
// Exact-f32 value-only scan (7 ops/pair), min-TREE reduction (min3-fusable,
// shallow chains), #pragma unroll 4 so ~12 LDS b128 reads stay in flight
// (~240cyc of VALU cover vs unroll 2's ~120 — R14 showed 31% idle from
// lgkmcnt stalls). Phase 2: bit-identical recompute + first-match ballots ->
// exact numpy first-flattened-index argmin.
#define SLICE 196

__global__ __launch_bounds__(256, 4) void clustgeo_scan_u4(
    const float* __restrict__ data,
    const int*   __restrict__ clusts,
    const int*   __restrict__ eidx,
    float*       __restrict__ out,
    int E)
{
    const int wave = threadIdx.x >> 6;
    const int lane = threadIdx.x & 63;
    const int t    = lane & 15;
    const int gsh  = lane & 48;
    const int e    = blockIdx.x * 16 + wave * 4 + (lane >> 4);
    const int ec   = e < E ? e : (E - 1);

    __shared__ __align__(16) float sx[4][4][SLICE];

    const int ca = eidx[ec];
    const int cb = eidx[E + ec];
    const int4 P1 = *reinterpret_cast<const int4*>(clusts + ca * 64 + 4 * t);
    const int4 P2 = *reinterpret_cast<const int4*>(clusts + cb * 64 + 4 * t);
    const float4 q10 = *reinterpret_cast<const float4*>(data + (size_t)P1.x * 4);
    const float4 q11 = *reinterpret_cast<const float4*>(data + (size_t)P1.y * 4);
    const float4 q12 = *reinterpret_cast<const float4*>(data + (size_t)P1.z * 4);
    const float4 q13 = *reinterpret_cast<const float4*>(data + (size_t)P1.w * 4);
    const float4 q20 = *reinterpret_cast<const float4*>(data + (size_t)P2.x * 4);
    const float4 q21 = *reinterpret_cast<const float4*>(data + (size_t)P2.y * 4);
    const float4 q22 = *reinterpret_cast<const float4*>(data + (size_t)P2.z * 4);
    const float4 q23 = *reinterpret_cast<const float4*>(data + (size_t)P2.w * 4);
    // Rows 4t+s of x1 (regs).
    const float r0x=q10.y, r0y=q10.z, r0z=q10.w;
    const float r1x=q11.y, r1y=q11.z, r1z=q11.w;
    const float r2x=q12.y, r2y=q12.z, r2z=q12.w;
    const float r3x=q13.y, r3y=q13.z, r3z=q13.w;
    // Cols 4t+s of x2 (regs; phase-2 source).
    const float c0x=q20.y, c0y=q20.z, c0z=q20.w;
    const float c1x=q21.y, c1y=q21.z, c1z=q21.w;
    const float c2x=q22.y, c2y=q22.z, c2z=q22.w;
    const float c3x=q23.y, c3y=q23.z, c3z=q23.w;

    float* slice = &sx[wave][lane >> 4][0];   // SoA: comp p at p*64 + col
    *reinterpret_cast<v4f*>(slice + 4 * t)       = (v4f){c0x, c1x, c2x, c3x};
    *reinterpret_cast<v4f*>(slice + 64 + 4 * t)  = (v4f){c0y, c1y, c2y, c3y};
    *reinterpret_cast<v4f*>(slice + 128 + 4 * t) = (v4f){c0z, c1z, c2z, c3z};
    // No barrier: each group reads only its own slice; same-wave LDS RAW is
    // ordered by compiler-inserted lgkmcnt waits (validated R3-R20).

    const v4f* SL = reinterpret_cast<const v4f*>(slice);   // comp p: [p*16+g]

    float a0 = FLT_MAX, a1 = FLT_MAX, a2 = FLT_MAX, a3 = FLT_MAX;
    #pragma unroll 4
    for (int g = 0; g < 16; ++g) {
        const v4f X = SL[g];
        const v4f Y = SL[16 + g];
        const v4f Z = SL[32 + g];
        {   // row 0: 4 d2 temps, tree min (min3-fusable)
            const float d0 = d2f(r0x, r0y, r0z, X.x, Y.x, Z.x);
            const float d1 = d2f(r0x, r0y, r0z, X.y, Y.y, Z.y);
            const float d2_ = d2f(r0x, r0y, r0z, X.z, Y.z, Z.z);
            const float d3 = d2f(r0x, r0y, r0z, X.w, Y.w, Z.w);
            a0 = fminf(fminf(fminf(d0, d1), fminf(d2_, d3)), a0);
        }
        {   // row 1
            const float d0 = d2f(r1x, r1y, r1z, X.x, Y.x, Z.x);
            const float d1 = d2f(r1x, r1y, r1z, X.y, Y.y, Z.y);
            const float d2_ = d2f(r1x, r1y, r1z, X.z, Y.z, Z.z);
            const float d3 = d2f(r1x, r1y, r1z, X.w, Y.w, Z.w);
            a1 = fminf(fminf(fminf(d0, d1), fminf(d2_, d3)), a1);
        }
        {   // row 2
            const float d0 = d2f(r2x, r2y, r2z, X.x, Y.x, Z.x);
            const float d1 = d2f(r2x, r2y, r2z, X.y, Y.y, Z.y);
            const float d2_ = d2f(r2x, r2y, r2z, X.z, Y.z, Z.z);
            const float d3 = d2f(r2x, r2y, r2z, X.w, Y.w, Z.w);
            a2 = fminf(fminf(fminf(d0, d1), fminf(d2_, d3)), a2);
        }
        {   // row 3
            const float d0 = d2f(r3x, r3y, r3z, X.x, Y.x, Z.x);
            const float d1 = d2f(r3x, r3y, r3z, X.y, Y.y, Z.y);
            const float d2_ = d2f(r3x, r3y, r3z, X.z, Y.z, Z.z);
            const float d3 = d2f(r3x, r3y, r3z, X.w, Y.w, Z.w);
            a3 = fminf(fminf(fminf(d0, d1), fminf(d2_, d3)), a3);
        }
    }
    const float m0 = a0, m1 = a1, m2 = a2, m3 = a3;

    float bmn = fminf(fminf(m0, m1), fminf(m2, m3));
    #pragma unroll
    for (int off = 8; off; off >>= 1) bmn = fminf(bmn, __shfl_xor(bmn, off, 64));

    // First row attaining min (row = 4t + slot: lexicographic (t, slot)).
    const unsigned g0 = (unsigned)(__ballot(m0 == bmn) >> gsh) & 0xFFFFu;
    const unsigned g1 = (unsigned)(__ballot(m1 == bmn) >> gsh) & 0xFFFFu;
    const unsigned g2 = (unsigned)(__ballot(m2 == bmn) >> gsh) & 0xFFFFu;
    const unsigned g3 = (unsigned)(__ballot(m3 == bmn) >> gsh) & 0xFFFFu;
    const int t1 = __builtin_ctz(g0 | g1 | g2 | g3);
    const int s1 = (g0 >> t1) & 1 ? 0 : (g1 >> t1) & 1 ? 1 : (g2 >> t1) & 1 ? 2 : 3;

    const float v1x = __shfl(sel4(s1, r0x, r1x, r2x, r3x), gsh + t1, 64);
    const float v1y = __shfl(sel4(s1, r0y, r1y, r2y, r3y), gsh + t1, 64);
    const float v1z = __shfl(sel4(s1, r0z, r1z, r2z, r3z), gsh + t1, 64);

    // Phase 2: bit-identical recompute of row i1 over this lane's 4 cols.
    const float d0 = d2f(v1x, v1y, v1z, c0x, c0y, c0z);
    const float d1 = d2f(v1x, v1y, v1z, c1x, c1y, c1z);
    const float d2_ = d2f(v1x, v1y, v1z, c2x, c2y, c2z);
    const float d3 = d2f(v1x, v1y, v1z, c3x, c3y, c3z);
    const unsigned h0 = (unsigned)(__ballot(d0 == bmn) >> gsh) & 0xFFFFu;
    const unsigned h1 = (unsigned)(__ballot(d1 == bmn) >> gsh) & 0xFFFFu;
    const unsigned h2 = (unsigned)(__ballot(d2_ == bmn) >> gsh) & 0xFFFFu;
    const unsigned h3 = (unsigned)(__ballot(d3 == bmn) >> gsh) & 0xFFFFu;
    const int t2 = __builtin_ctz(h0 | h1 | h2 | h3);
    const int s2 = (h0 >> t2) & 1 ? 0 : (h1 >> t2) & 1 ? 1 : (h2 >> t2) & 1 ? 2 : 3;

    const float v2x = __shfl(sel4(s2, c0x, c1x, c2x, c3x), gsh + t2, 64);
    const float v2y = __shfl(sel4(s2, c0y, c1y, c2y, c3y), gsh + t2, 64);
    const float v2z = __shfl(sel4(s2, c0z, c1z, c2z, c3z), gsh + t2, 64);

    float dx = v1x - v2x, dy = v1y - v2y, dz = v1z - v2z;
    const float lend = sqrtf(dx * dx + dy * dy + dz * dz);
    if (lend > 0.f) {
        const float inv = 1.0f / lend;   // 1 divide + 3 muls
        dx *= inv; dy *= inv; dz *= inv;
    }

    if (e < E) {
        float* orow = out + (size_t)e * 19;
        float o;
        if (t < 3)       o = sel3(t,     v1x, v1y, v1z);
        else if (t < 6)  o = sel3(t - 3, v2x, v2y, v2z);
        else if (t < 9)  o = sel3(t - 6, dx, dy, dz);
        else if (t == 9) o = lend;
        else {
            const int k = t - 10;
            o = sel3(k / 3, dx, dy, dz) * sel3(k % 3, dx, dy, dz);
        }
        orow[t] = o;
        if (t < 3) {
            const int k = t + 6;   // elements 16,17,18 = B[6..8]
            orow[16 + t] = sel3(k / 3, dx, dy, dz) * sel3(k % 3, dx, dy, dz);
        }
    }
}

extern "C" void kernel_launch(void* const* d_in, const int* in_sizes, int n_in,
                              void* d_out, int out_size, void* d_ws, size_t ws_size,
                              hipStream_t stream) {
    const float* data   = (const float*)d_in[0];
    const int*   clusts = (const int*)d_in[1];
    const int*   eidx   = (const int*)d_in[2];
    float*       out    = (float*)d_out;
    const int E = in_sizes[2] / 2;            // edge_index is (2, E)
    const int blocks = (E + 15) / 16;         // 16 edges per block (4 waves x 4)
    clustgeo_scan_u4<<<blocks, 256, 0, stream>>>(data, clusts, eidx, out, E);
}